// Round 4
// baseline (576.012 us; speedup 1.0000x reference)
//
#include <hip/hip_runtime.h>
#include <math.h>

#define Bv   64
#define Nv   900
#define Mv   64
#define NCls 128
#define NCOLS (Nv + 1)          // 901 columns incl. dummy col 0
#define KREG 15                 // columns per lane: j = t + 64k, k=0..14
#define INFV 1000000000.0f

// uniform dynamic read of a constant-indexed register array (stays in VGPRs)
#define SEL15(arr, kidx, dst) do {            \
    int _s = arr[0];                          \
    _Pragma("unroll")                         \
    for (int _kk = 1; _kk < KREG; _kk++)      \
        _s = ((kidx) == _kk) ? arr[_kk] : _s; \
    (dst) = _s;                               \
} while (0)

// uniform dynamic write (lane-targeted, register-indexed by uniform kidx)
#define SET15(arr, kidx, val) do {            \
    _Pragma("unroll")                         \
    for (int _kk = 0; _kk < KREG; _kk++)      \
        if ((kidx) == _kk) arr[_kk] = (val);  \
} while (0)

// ---- order-preserving float <-> sortable u32 (bit-exact round trip) --------
__device__ __forceinline__ unsigned f2s(float f) {
    unsigned x = __float_as_uint(f);
    return x ^ ((unsigned)((int)x >> 31) | 0x80000000u);
}
__device__ __forceinline__ float s2f(unsigned s) {
    unsigned x = ((int)s < 0) ? (s ^ 0x80000000u) : ~s;
    return __uint_as_float(x);
}

// ---- wave64 min-reduce of packed (hi=sortable value, lo=index) via DPP -----
// rocPRIM pattern: row_shr 1/2/4/8, row_bcast:15 (rows 1,3), row_bcast:31
// (rows 2,3); full min lands in lane 63; broadcast via readlane.
// Lexicographic compare => min value, then min index (matches first-index
// argmin tie-break of the verified shuffle version).
__device__ __forceinline__ void wave_min_pair(unsigned& hi, unsigned& lo) {
#define DPP_STEP(ctrl, rmask)                                                   \
    {                                                                           \
        unsigned ohi = (unsigned)__builtin_amdgcn_update_dpp(                   \
            (int)hi, (int)hi, ctrl, rmask, 0xf, false);                         \
        unsigned olo = (unsigned)__builtin_amdgcn_update_dpp(                   \
            (int)lo, (int)lo, ctrl, rmask, 0xf, false);                         \
        bool take = (ohi < hi) || (ohi == hi && olo < lo);                      \
        hi = take ? ohi : hi;                                                   \
        lo = take ? olo : lo;                                                   \
    }
    DPP_STEP(0x111, 0xf)   // row_shr:1
    DPP_STEP(0x112, 0xf)   // row_shr:2
    DPP_STEP(0x114, 0xf)   // row_shr:4
    DPP_STEP(0x118, 0xf)   // row_shr:8   -> lanes 15/31/47/63 hold row mins
    DPP_STEP(0x142, 0xa)   // row_bcast:15 -> lane 31: min(0..31), 63: min(32..63)
    DPP_STEP(0x143, 0xc)   // row_bcast:31 -> lane 63: min(0..63)
#undef DPP_STEP
    hi = (unsigned)__builtin_amdgcn_readlane((int)hi, 63);
    lo = (unsigned)__builtin_amdgcn_readlane((int)lo, 63);
}

// ---------------------------------------------------------------------------
// Kernel 1: cost matrix. One wave per (b, 4 consecutive n). labels/boxes
// hoisted out of the n-loop (verified R3).
// ---------------------------------------------------------------------------
__global__ __launch_bounds__(64) void cost_kernel(
    const float* __restrict__ logits,   // [B,N,128]
    const float* __restrict__ corners,  // [B,N,8,3]
    const int*   __restrict__ labels,   // [B,64]
    const float* __restrict__ boxes,    // [B,64,7]
    float*       __restrict__ C)        // [B,N,64]
{
    const int b = blockIdx.y, t = threadIdx.x;
    const int n0 = blockIdx.x * 4;

    const int    lbl = labels[b * Mv + t];
    const float* bx  = boxes + ((long)b * Mv + t) * 7;
    const float bx0 = bx[0], bx1 = bx[1], bx2 = bx[2];

    __shared__ float probs[NCls];

    #pragma unroll
    for (int i = 0; i < 4; ++i) {
        const int  n  = n0 + i;
        const long bn = (long)b * Nv + n;

        const float2 l2 = ((const float2*)(logits + bn * NCls))[t];
        float e0 = expf(l2.x), e1 = expf(l2.y);
        ((float2*)probs)[t] = make_float2(e0, e1);

        float s = e0 + e1;
        #pragma unroll
        for (int off = 1; off < 64; off <<= 1) s += __shfl_xor(s, off, 64);

        const float* cp = corners + bn * 24;
        float cx = 0.f, cy = 0.f, cz = 0.f;
        if (t < 8) { cx = cp[3 * t]; cy = cp[3 * t + 1]; cz = cp[3 * t + 2]; }
        #pragma unroll
        for (int off = 1; off < 8; off <<= 1) {
            cx += __shfl_xor(cx, off, 64);
            cy += __shfl_xor(cy, off, 64);
            cz += __shfl_xor(cz, off, 64);
        }
        cx = __shfl(cx, 0, 64) * 0.125f;
        cy = __shfl(cy, 0, 64) * 0.125f;
        cz = __shfl(cz, 0, 64) * 0.125f;

        __syncthreads();   // probs visible
        float pm = probs[lbl] / s;
        float dx = cx - bx0, dy = cy - bx1, dz = cz - bx2;
        C[bn * Mv + t] = 5.0f * sqrtf(dx * dx + dy * dy + dz * dz) - pm;
        __syncthreads();   // before next iteration overwrites probs
    }
}

// ---------------------------------------------------------------------------
// Kernel 1.5 (verified R2): C [b][n][m] -> CT [b][m][n], LDS-tiled.
// ---------------------------------------------------------------------------
__global__ __launch_bounds__(256) void transpose_kernel(
    const float* __restrict__ C,    // [B,900,64]
    float*       __restrict__ CT)   // [B,64,900]
{
    __shared__ float tile[64][65];
    const int b  = blockIdx.y;
    const int n0 = blockIdx.x * 64;
    const int t  = threadIdx.x & 63;
    const int w  = threadIdx.x >> 6;

    const float* cb = C + (size_t)b * Nv * Mv;
    #pragma unroll
    for (int r = 0; r < 16; ++r) {
        int n = n0 + w * 16 + r;
        if (n < Nv) tile[w * 16 + r][t] = cb[(size_t)n * Mv + t];
    }
    __syncthreads();

    float* ctb = CT + (size_t)b * Mv * Nv;
    const int n = n0 + t;
    if (n < Nv) {
        #pragma unroll
        for (int r = 0; r < 16; ++r) {
            int m = w * 16 + r;
            ctb[(size_t)m * Nv + n] = tile[t][m];
        }
    }
}

// ---------------------------------------------------------------------------
// Kernel 2: LAPJV-style LSA, one wave per batch, all state in registers.
//  USECT=1 (main path):
//   Phase A: per-row argmin by reading CT (not C): for each row m, 15
//     coalesced loads + DPP packed argmin. Crucially this STREAMS all of
//     CT through the LOCAL XCD L2 right before Phase C (R3 lesson: CT
//     written earlier gets evicted; the reader must be the warmer).
//   Phase C: Dijkstra scans read CT rows -> 15 coalesced LOCAL-L2 hits
//     (~250cy) instead of 960 gather requests (~900cy issue+wait), and the
//     64-lane argmin is a DPP chain (~80cy) instead of ds-shuffle (~400cy).
//  USECT=0: verified fallback = original gather + shuffle reduce.
// Exactness: CT values are bit-identical copies of C; packed lexicographic
// min reproduces the exact (value, lowest-index) tie-break of the verified
// version; delta is reconstructed bit-exact from the sortable encoding.
// ---------------------------------------------------------------------------
template <int USECT>
__global__ __launch_bounds__(64) void lsa_kernel(
    const float* __restrict__ C,    // [B, N, M] = [64,900,64]
    const float* __restrict__ CT,   // [B, M, N] = [64,64,900] ws (or null)
    float* __restrict__ outPred, float* __restrict__ outTgt)
{
    const int b = blockIdx.x;
    const int t = threadIdx.x;
    const float* cb  = C + (size_t)b * Nv * Mv;
    const float* ctb = USECT ? (CT + (size_t)b * Mv * Nv) : (const float*)0;

    float rowmin = INFV;
    int   rown   = 0;

    if (USECT) {
        // ---- Phase A: argmin of each CT row; warms local L2 with all of CT
        #pragma unroll 2
        for (int m = 0; m < Mv; ++m) {
            const float* rm = ctb + (size_t)m * Nv;
            float bv = INFV; int bn = 0;
            #pragma unroll
            for (int c = 0; c < KREG; ++c) {
                int n = (c << 6) + t;
                if (n < Nv) {
                    float x = rm[n];
                    if (x < bv) { bv = x; bn = n; }   // first-n wins ties
                }
            }
            unsigned hi = f2s(bv), lo = (unsigned)bn;
            wave_min_pair(hi, lo);
            if (t == m) { rowmin = s2f(hi); rown = (int)lo; }
        }
    } else {
        // ---- verified fallback: 4 disjoint ranges for ILP, gather layout
        float mv0 = INFV, mv1 = INFV, mv2 = INFV, mv3 = INFV;
        int   mj0 = 0,    mj1 = 0,    mj2 = 0,    mj3 = 0;
        #pragma unroll 5
        for (int n = 0; n < 225; ++n) {
            float c0 = cb[(size_t)(n      ) * Mv + t];
            float c1 = cb[(size_t)(n + 225) * Mv + t];
            float c2 = cb[(size_t)(n + 450) * Mv + t];
            float c3 = cb[(size_t)(n + 675) * Mv + t];
            if (c0 < mv0) { mv0 = c0; mj0 = n;       }
            if (c1 < mv1) { mv1 = c1; mj1 = n + 225; }
            if (c2 < mv2) { mv2 = c2; mj2 = n + 450; }
            if (c3 < mv3) { mv3 = c3; mj3 = n + 675; }
        }
        rowmin = mv0; rown = mj0;
        if (mv1 < rowmin) { rowmin = mv1; rown = mj1; }
        if (mv2 < rowmin) { rowmin = mv2; rown = mj2; }
        if (mv3 < rowmin) { rowmin = mv3; rown = mj3; }
    }

    float u_reg = rowmin;            // lane l holds u[l+1]
    const int jcol = rown + 1;       // column index in 1..900

    // ---- Phase B: duplicate detection (first occurrence wins)
    bool isdup = false;
    #pragma unroll
    for (int s = 1; s < 64; ++s) {
        int oj = __shfl(jcol, (t + 64 - s) & 63, 64);
        isdup |= (oj == jcol) && (s <= t);
    }
    unsigned long long pending = __ballot(isdup);

    int   p_reg[KREG], way_reg[KREG];
    float v_reg[KREG], minv[KREG];
    #pragma unroll
    for (int k = 0; k < KREG; k++) { p_reg[k] = 0; way_reg[k] = 0; v_reg[k] = 0.f; }

    int rowcol = isdup ? 0 : jcol;   // lane i: column assigned to row i+1

    // scatter winners into distributed p[] (independent iterations)
    #pragma unroll 8
    for (int i = 0; i < 64; ++i) {
        int jb = __shfl(jcol, i, 64);
        if (!((pending >> i) & 1ull) && t == (jb & 63))
            SET15(p_reg, jb >> 6, i + 1);
    }

    // ---- Phase C: Dijkstra phases for conflicted rows only
    while (pending) {
        const int i1v = __ffsll(pending);    // bit pos +1 == row index (1-based)
        pending &= pending - 1;

        unsigned int usedMask = 0;
        unsigned long long rowMask = 0;
        #pragma unroll
        for (int k = 0; k < KREG; k++) minv[k] = INFV;

        int j0 = 0;
        int i0 = i1v;
        while (true) {
            if ((j0 & 63) == t) usedMask |= 1u << (j0 >> 6);
            rowMask |= 1ull << (i0 - 1);
            const float u_i0 = __shfl(u_reg, i0 - 1, 64);
            const float* crow = USECT ? (ctb + (size_t)(i0 - 1) * Nv) : (const float*)0;

            float bestv = INFV;
            int   bestj = NCOLS;
            #pragma unroll
            for (int k = 0; k < KREG; k++) {
                int j = t + (k << 6);
                if (j < NCOLS) {
                    float c;
                    if (j == 0)      c = 0.0f;
                    else if (USECT)  c = crow[j - 1];                             // coalesced, local L2
                    else             c = cb[(((size_t)(j - 1)) << 6) + (i0 - 1)]; // gather
                    float cur = (c - u_i0) - v_reg[k];
                    bool used = (usedMask >> k) & 1u;
                    if (!used && cur < minv[k]) { minv[k] = cur; way_reg[k] = j0; }
                    float mval = used ? INFV : minv[k];
                    if (mval < bestv) { bestv = mval; bestj = j; }   // first-k wins
                }
            }
            float delta; int bestjAll;
            if (USECT) {
                unsigned hi = f2s(bestv), lo = (unsigned)bestj;
                wave_min_pair(hi, lo);                  // ~80cy DPP chain
                delta = s2f(hi); bestjAll = (int)lo;
            } else {
                #pragma unroll
                for (int off = 1; off < 64; off <<= 1) {
                    float ov = __shfl_xor(bestv, off, 64);
                    int   oj = __shfl_xor(bestj, off, 64);
                    if (ov < bestv || (ov == bestv && oj < bestj)) { bestv = ov; bestj = oj; }
                }
                delta = bestv; bestjAll = bestj;
            }

            if ((rowMask >> t) & 1ull) u_reg += delta;
            #pragma unroll
            for (int k = 0; k < KREG; k++) {
                if ((usedMask >> k) & 1u) v_reg[k] -= delta;
                else                      minv[k] -= delta;
            }

            j0 = bestjAll;
            const int k0 = j0 >> 6, l0 = j0 & 63;
            int ptmp; SEL15(p_reg, k0, ptmp);
            i0 = __shfl(ptmp, l0, 64);
            if (i0 == 0) break;              // free column reached
        }

        // backtrack: reassign columns along augmenting path
        while (j0 != 0) {
            const int k0 = j0 >> 6, l0 = j0 & 63;
            int wtmp; SEL15(way_reg, k0, wtmp);
            const int jprev = __shfl(wtmp, l0, 64);
            int pv;
            if (jprev == 0) {
                pv = i1v;
            } else {
                int ptmp; SEL15(p_reg, jprev >> 6, ptmp);
                pv = __shfl(ptmp, jprev & 63, 64);
            }
            if (t == l0) SET15(p_reg, k0, pv);
            if (t == pv - 1) rowcol = j0;    // maintain row->column mirror
            j0 = jprev;
        }
    }

    outPred[b * Mv + t] = (float)(rowcol - 1);
    outTgt[b * Mv + t]  = (float)t;
}

// ---------------------------------------------------------------------------
extern "C" void kernel_launch(void* const* d_in, const int* in_sizes, int n_in,
                              void* d_out, int out_size, void* d_ws, size_t ws_size,
                              hipStream_t stream)
{
    (void)in_sizes; (void)n_in; (void)out_size;

    const float* logits  = (const float*)d_in[0];   // [64,900,128] f32
    const float* corners = (const float*)d_in[1];   // [64,900,8,3] f32
    const int*   labels  = (const int*)  d_in[2];   // [64,64] i32
    const float* boxes   = (const float*)d_in[3];   // [64,64,7] f32

    float* out  = (float*)d_out;
    float* Cc   = out;                               // [64,900,64]
    float* pred = out + (size_t)Bv * Nv * Mv;        // [64,64] as f32
    float* tgt  = pred + (size_t)Bv * Mv;            // [64,64] as f32

    cost_kernel<<<dim3(225, Bv), 64, 0, stream>>>(logits, corners, labels, boxes, Cc);

    const size_t CT_BYTES = (size_t)Bv * Mv * Nv * sizeof(float);   // 14.75 MB
    if (d_ws != nullptr && ws_size >= CT_BYTES) {
        float* CT = (float*)d_ws;
        transpose_kernel<<<dim3(15, Bv), 256, 0, stream>>>(Cc, CT);
        lsa_kernel<1><<<Bv, 64, 0, stream>>>(Cc, CT, pred, tgt);
    } else {
        lsa_kernel<0><<<Bv, 64, 0, stream>>>(Cc, nullptr, pred, tgt);
    }
}

// Round 5
// 269.755 us; speedup vs baseline: 2.1353x; 2.1353x over previous
//
#include <hip/hip_runtime.h>
#include <math.h>

#define Bv   64
#define Nv   900
#define Mv   64
#define NCls 128
#define NCOLS (Nv + 1)          // 901 columns incl. dummy col 0
#define KREG 15                 // columns per lane: j = t + 64k, k=0..14
#define INFV 1000000000.0f

// uniform dynamic read of a constant-indexed register array (stays in VGPRs)
#define SEL15(arr, kidx, dst) do {            \
    int _s = arr[0];                          \
    _Pragma("unroll")                         \
    for (int _kk = 1; _kk < KREG; _kk++)      \
        _s = ((kidx) == _kk) ? arr[_kk] : _s; \
    (dst) = _s;                               \
} while (0)

// uniform dynamic write (lane-targeted, register-indexed by uniform kidx)
#define SET15(arr, kidx, val) do {            \
    _Pragma("unroll")                         \
    for (int _kk = 0; _kk < KREG; _kk++)      \
        if ((kidx) == _kk) arr[_kk] = (val);  \
} while (0)

// ---- order-preserving float <-> sortable u32 (bit-exact round trip) --------
__device__ __forceinline__ unsigned f2s(float f) {
    unsigned x = __float_as_uint(f);
    return x ^ ((unsigned)((int)x >> 31) | 0x80000000u);
}
__device__ __forceinline__ float s2f(unsigned s) {
    unsigned x = ((int)s < 0) ? (s ^ 0x80000000u) : ~s;
    return __uint_as_float(x);
}

// ---- wave64 min-reduce of packed (hi=sortable value, lo=index) via DPP -----
// HW-verified in R4 (passed). Lexicographic (value, index) compare ==
// exact tie-break of the verified shuffle reduce. VALU-latency chain
// (~100cy) instead of 6 dependent ds-shuffle hops (~300-400cy).
__device__ __forceinline__ void wave_min_pair(unsigned& hi, unsigned& lo) {
#define DPP_STEP(ctrl, rmask)                                                   \
    {                                                                           \
        unsigned ohi = (unsigned)__builtin_amdgcn_update_dpp(                   \
            (int)hi, (int)hi, ctrl, rmask, 0xf, false);                         \
        unsigned olo = (unsigned)__builtin_amdgcn_update_dpp(                   \
            (int)lo, (int)lo, ctrl, rmask, 0xf, false);                         \
        bool take = (ohi < hi) || (ohi == hi && olo < lo);                      \
        hi = take ? ohi : hi;                                                   \
        lo = take ? olo : lo;                                                   \
    }
    DPP_STEP(0x111, 0xf)   // row_shr:1
    DPP_STEP(0x112, 0xf)   // row_shr:2
    DPP_STEP(0x114, 0xf)   // row_shr:4
    DPP_STEP(0x118, 0xf)   // row_shr:8   -> lanes 15/31/47/63 hold row mins
    DPP_STEP(0x142, 0xa)   // row_bcast:15 -> lane 31: min(0..31), 63: min(32..63)
    DPP_STEP(0x143, 0xc)   // row_bcast:31 -> lane 63: min(0..63)
#undef DPP_STEP
    hi = (unsigned)__builtin_amdgcn_readlane((int)hi, 63);
    lo = (unsigned)__builtin_amdgcn_readlane((int)lo, 63);
}

// ---------------------------------------------------------------------------
// Kernel 1: cost matrix. One wave per (b, 4 consecutive n). labels/boxes
// hoisted out of the n-loop (verified R3/R4: ~15-20us vs 67us for 1-n/wave).
// ---------------------------------------------------------------------------
__global__ __launch_bounds__(64) void cost_kernel(
    const float* __restrict__ logits,   // [B,N,128]
    const float* __restrict__ corners,  // [B,N,8,3]
    const int*   __restrict__ labels,   // [B,64]
    const float* __restrict__ boxes,    // [B,64,7]
    float*       __restrict__ C)        // [B,N,64]
{
    const int b = blockIdx.y, t = threadIdx.x;
    const int n0 = blockIdx.x * 4;

    const int    lbl = labels[b * Mv + t];
    const float* bx  = boxes + ((long)b * Mv + t) * 7;
    const float bx0 = bx[0], bx1 = bx[1], bx2 = bx[2];

    __shared__ float probs[NCls];

    #pragma unroll
    for (int i = 0; i < 4; ++i) {
        const int  n  = n0 + i;
        const long bn = (long)b * Nv + n;

        const float2 l2 = ((const float2*)(logits + bn * NCls))[t];
        float e0 = expf(l2.x), e1 = expf(l2.y);
        ((float2*)probs)[t] = make_float2(e0, e1);

        float s = e0 + e1;
        #pragma unroll
        for (int off = 1; off < 64; off <<= 1) s += __shfl_xor(s, off, 64);

        const float* cp = corners + bn * 24;
        float cx = 0.f, cy = 0.f, cz = 0.f;
        if (t < 8) { cx = cp[3 * t]; cy = cp[3 * t + 1]; cz = cp[3 * t + 2]; }
        #pragma unroll
        for (int off = 1; off < 8; off <<= 1) {
            cx += __shfl_xor(cx, off, 64);
            cy += __shfl_xor(cy, off, 64);
            cz += __shfl_xor(cz, off, 64);
        }
        cx = __shfl(cx, 0, 64) * 0.125f;
        cy = __shfl(cy, 0, 64) * 0.125f;
        cz = __shfl(cz, 0, 64) * 0.125f;

        __syncthreads();   // probs visible
        float pm = probs[lbl] / s;
        float dx = cx - bx0, dy = cy - bx1, dz = cz - bx2;
        C[bn * Mv + t] = 5.0f * sqrtf(dx * dx + dy * dy + dz * dz) - pm;
        __syncthreads();   // before next iteration overwrites probs
    }
}

// ---------------------------------------------------------------------------
// Kernel 2: LAPJV-style LSA, one wave per batch, all state in registers.
// R4 lesson: the GATHER layout is cache-optimal for Phase C -- the same ~960
// lines are re-touched every iteration (i0 only moves the 4B offset within
// each 256B block), so the working set stays hot in L1/L2. CT/transpose
// variants (R2-R4) all regressed; reverted to the verified R1 structure.
// This round's isolated changes (values bit-identical, ordering preserved):
//   1. Phase C reduce: ds-shuffle butterfly -> DPP packed argmin.
//   2. Next-row gather prefetched BEFORE the u/v/minv VALU updates
//      (i_next known early; memory wait overlaps ~300cy of updates).
// ---------------------------------------------------------------------------
__global__ __launch_bounds__(64) void lsa_kernel(
    const float* __restrict__ C,    // [B, N, M] = [64,900,64]
    float* __restrict__ outPred, float* __restrict__ outTgt)
{
    const int b = blockIdx.x;
    const int t = threadIdx.x;
    const float* cb = C + (size_t)b * Nv * Mv;

    // ---- Phase A: row argmin (lane t = row t+1); 4 disjoint ranges for ILP
    float mv0 = INFV, mv1 = INFV, mv2 = INFV, mv3 = INFV;
    int   mj0 = 0,    mj1 = 0,    mj2 = 0,    mj3 = 0;
    #pragma unroll 5
    for (int n = 0; n < 225; ++n) {
        float c0 = cb[(size_t)(n      ) * Mv + t];
        float c1 = cb[(size_t)(n + 225) * Mv + t];
        float c2 = cb[(size_t)(n + 450) * Mv + t];
        float c3 = cb[(size_t)(n + 675) * Mv + t];
        if (c0 < mv0) { mv0 = c0; mj0 = n;       }
        if (c1 < mv1) { mv1 = c1; mj1 = n + 225; }
        if (c2 < mv2) { mv2 = c2; mj2 = n + 450; }
        if (c3 < mv3) { mv3 = c3; mj3 = n + 675; }
    }
    // merge (earlier range wins ties -> first-index; irrelevant to optimum)
    float rowmin = mv0; int rown = mj0;
    if (mv1 < rowmin) { rowmin = mv1; rown = mj1; }
    if (mv2 < rowmin) { rowmin = mv2; rown = mj2; }
    if (mv3 < rowmin) { rowmin = mv3; rown = mj3; }

    float u_reg = rowmin;            // lane l holds u[l+1]
    const int jcol = rown + 1;       // column index in 1..900

    // ---- Phase B: duplicate detection (first occurrence wins)
    bool isdup = false;
    #pragma unroll
    for (int s = 1; s < 64; ++s) {
        int oj = __shfl(jcol, (t + 64 - s) & 63, 64);
        isdup |= (oj == jcol) && (s <= t);
    }
    unsigned long long pending = __ballot(isdup);

    int   p_reg[KREG], way_reg[KREG];
    float v_reg[KREG], minv[KREG];
    #pragma unroll
    for (int k = 0; k < KREG; k++) { p_reg[k] = 0; way_reg[k] = 0; v_reg[k] = 0.f; }

    int rowcol = isdup ? 0 : jcol;   // lane i: column assigned to row i+1

    // scatter winners into distributed p[] (independent iterations)
    #pragma unroll 8
    for (int i = 0; i < 64; ++i) {
        int jb = __shfl(jcol, i, 64);
        if (!((pending >> i) & 1ull) && t == (jb & 63))
            SET15(p_reg, jb >> 6, i + 1);
    }

    // ---- Phase C: Dijkstra phases for conflicted rows only
    while (pending) {
        const int i1v = __ffsll(pending);    // bit pos +1 == row index (1-based)
        pending &= pending - 1;

        unsigned int usedMask = 0;
        unsigned long long rowMask = 0;
        #pragma unroll
        for (int k = 0; k < KREG; k++) minv[k] = INFV;

        int j0 = 0;
        int i0 = i1v;

        // prefetch row i0's gather into registers
        float crow[KREG];
        #pragma unroll
        for (int k = 0; k < KREG; k++) {
            int j = t + (k << 6);
            crow[k] = (j >= 1 && j < NCOLS)
                      ? cb[(((size_t)(j - 1)) << 6) + (i0 - 1)] : 0.0f;
        }

        while (true) {
            if ((j0 & 63) == t) usedMask |= 1u << (j0 >> 6);
            rowMask |= 1ull << (i0 - 1);
            const float u_i0 = __shfl(u_reg, i0 - 1, 64);

            float bestv = INFV;
            int   bestj = NCOLS;
            #pragma unroll
            for (int k = 0; k < KREG; k++) {
                int j = t + (k << 6);
                if (j < NCOLS) {
                    float c   = (j == 0) ? 0.0f : crow[k];
                    float cur = (c - u_i0) - v_reg[k];
                    bool used = (usedMask >> k) & 1u;
                    if (!used && cur < minv[k]) { minv[k] = cur; way_reg[k] = j0; }
                    float mval = used ? INFV : minv[k];
                    if (mval < bestv) { bestv = mval; bestj = j; }
                }
            }
            unsigned hi = f2s(bestv), lo = (unsigned)bestj;
            wave_min_pair(hi, lo);
            const float delta = s2f(hi);

            j0 = (int)lo;
            const int k0 = j0 >> 6, l0 = j0 & 63;
            int ptmp; SEL15(p_reg, k0, ptmp);
            const int inext = __shfl(ptmp, l0, 64);

            // issue next row's gather NOW; its latency overlaps the updates
            if (inext != 0) {
                #pragma unroll
                for (int k = 0; k < KREG; k++) {
                    int j = t + (k << 6);
                    crow[k] = (j >= 1 && j < NCOLS)
                              ? cb[(((size_t)(j - 1)) << 6) + (inext - 1)] : 0.0f;
                }
            }

            if ((rowMask >> t) & 1ull) u_reg += delta;
            #pragma unroll
            for (int k = 0; k < KREG; k++) {
                if ((usedMask >> k) & 1u) v_reg[k] -= delta;
                else                      minv[k] -= delta;
            }

            i0 = inext;
            if (i0 == 0) break;              // free column reached
        }

        // backtrack: reassign columns along augmenting path
        while (j0 != 0) {
            const int k0 = j0 >> 6, l0 = j0 & 63;
            int wtmp; SEL15(way_reg, k0, wtmp);
            const int jprev = __shfl(wtmp, l0, 64);
            int pv;
            if (jprev == 0) {
                pv = i1v;
            } else {
                int ptmp; SEL15(p_reg, jprev >> 6, ptmp);
                pv = __shfl(ptmp, jprev & 63, 64);
            }
            if (t == l0) SET15(p_reg, k0, pv);
            if (t == pv - 1) rowcol = j0;    // maintain row->column mirror
            j0 = jprev;
        }
    }

    outPred[b * Mv + t] = (float)(rowcol - 1);
    outTgt[b * Mv + t]  = (float)t;
}

// ---------------------------------------------------------------------------
extern "C" void kernel_launch(void* const* d_in, const int* in_sizes, int n_in,
                              void* d_out, int out_size, void* d_ws, size_t ws_size,
                              hipStream_t stream)
{
    (void)in_sizes; (void)n_in; (void)out_size; (void)d_ws; (void)ws_size;

    const float* logits  = (const float*)d_in[0];   // [64,900,128] f32
    const float* corners = (const float*)d_in[1];   // [64,900,8,3] f32
    const int*   labels  = (const int*)  d_in[2];   // [64,64] i32
    const float* boxes   = (const float*)d_in[3];   // [64,64,7] f32

    float* out  = (float*)d_out;
    float* Cc   = out;                               // [64,900,64]
    float* pred = out + (size_t)Bv * Nv * Mv;        // [64,64] as f32
    float* tgt  = pred + (size_t)Bv * Mv;            // [64,64] as f32

    cost_kernel<<<dim3(225, Bv), 64, 0, stream>>>(logits, corners, labels, boxes, Cc);
    lsa_kernel<<<Bv, 64, 0, stream>>>(Cc, pred, tgt);
}

// Round 6
// 235.659 us; speedup vs baseline: 2.4443x; 1.1447x over previous
//
#include <hip/hip_runtime.h>
#include <math.h>

#define Bv   64
#define Nv   900
#define Mv   64
#define NCls 128
#define NCOLS (Nv + 1)          // 901 columns incl. dummy col 0
#define KREG 15                 // columns per lane: j = t + 64k, k=0..14
#define INFV 1000000000.0f
#define BIGV 1.0e18f            // sentinel for used/invalid slots: cur stays >> INFV

// uniform dynamic read of a constant-indexed register array (stays in VGPRs)
#define SEL15(arr, kidx, dst) do {            \
    int _s = arr[0];                          \
    _Pragma("unroll")                         \
    for (int _kk = 1; _kk < KREG; _kk++)      \
        _s = ((kidx) == _kk) ? arr[_kk] : _s; \
    (dst) = _s;                               \
} while (0)

// uniform dynamic write (lane-targeted, register-indexed by uniform kidx)
#define SET15(arr, kidx, val) do {            \
    _Pragma("unroll")                         \
    for (int _kk = 0; _kk < KREG; _kk++)      \
        if ((kidx) == _kk) arr[_kk] = (val);  \
} while (0)

// ---- wave64 reduces via DPP (rocPRIM pattern, HW-verified R4/R5) -----------
// row_shr:1/2/4/8 then row_bcast:15 (rows1,3) + row_bcast:31 (rows2,3);
// result in lane 63, broadcast by readlane.
__device__ __forceinline__ float wave_min_f32(float x) {
#define MSTEP(ctrl, rmask)                                                \
    {                                                                     \
        int o = __builtin_amdgcn_update_dpp(__float_as_int(x),            \
                __float_as_int(x), ctrl, rmask, 0xf, false);              \
        x = fminf(x, __int_as_float(o));                                  \
    }
    MSTEP(0x111, 0xf) MSTEP(0x112, 0xf) MSTEP(0x114, 0xf) MSTEP(0x118, 0xf)
    MSTEP(0x142, 0xa) MSTEP(0x143, 0xc)
#undef MSTEP
    return __int_as_float(__builtin_amdgcn_readlane(__float_as_int(x), 63));
}

__device__ __forceinline__ unsigned wave_min_u32(unsigned x) {
#define USTEP(ctrl, rmask)                                                \
    {                                                                     \
        unsigned o = (unsigned)__builtin_amdgcn_update_dpp((int)x,        \
                     (int)x, ctrl, rmask, 0xf, false);                    \
        x = (o < x) ? o : x;                                              \
    }
    USTEP(0x111, 0xf) USTEP(0x112, 0xf) USTEP(0x114, 0xf) USTEP(0x118, 0xf)
    USTEP(0x142, 0xa) USTEP(0x143, 0xc)
#undef USTEP
    return (unsigned)__builtin_amdgcn_readlane((int)x, 63);
}

__device__ __forceinline__ float wave_sum_f32(float x) {
#define SSTEP(ctrl, rmask)                                                \
    {                                                                     \
        int o = __builtin_amdgcn_update_dpp(0, __float_as_int(x),         \
                                            ctrl, rmask, 0xf, false);     \
        x += __int_as_float(o);                                           \
    }
    SSTEP(0x111, 0xf) SSTEP(0x112, 0xf) SSTEP(0x114, 0xf) SSTEP(0x118, 0xf)
    SSTEP(0x142, 0xa) SSTEP(0x143, 0xc)
#undef SSTEP
    return __int_as_float(__builtin_amdgcn_readlane(__float_as_int(x), 63));
}

// ---------------------------------------------------------------------------
// Kernel 1: cost matrix. 256-thread blocks = 4 waves, ONE n per wave,
// grid (225, 64) -> 900 n exactly. No LDS, no __syncthreads:
//  - softmax denom: DPP wave sum (order differs from jax sum; absmax tol 0.06)
//  - prob lookup: 2x ds_bpermute from the lane owning classes 2k,2k+1
//  - center: wave sum over the 8 corner lanes (others contribute 0)
// ---------------------------------------------------------------------------
__global__ __launch_bounds__(256) void cost_kernel(
    const float* __restrict__ logits,   // [B,N,128]
    const float* __restrict__ corners,  // [B,N,8,3]
    const int*   __restrict__ labels,   // [B,64]
    const float* __restrict__ boxes,    // [B,64,7]
    float*       __restrict__ C)        // [B,N,64]
{
    const int b = blockIdx.y;
    const int n = blockIdx.x * 4 + (threadIdx.x >> 6);
    const int t = threadIdx.x & 63;
    const long bn = (long)b * Nv + n;

    // issue all loads up front (logits, corners, labels, boxes overlap)
    const float2 l2 = ((const float2*)(logits + bn * NCls))[t];
    const float* cp = corners + bn * 24;
    float cx = 0.f, cy = 0.f, cz = 0.f;
    if (t < 8) { cx = cp[3 * t]; cy = cp[3 * t + 1]; cz = cp[3 * t + 2]; }
    const int    lbl = labels[b * Mv + t];
    const float* bx  = boxes + ((long)b * Mv + t) * 7;
    const float bx0 = bx[0], bx1 = bx[1], bx2 = bx[2];

    float e0 = expf(l2.x), e1 = expf(l2.y);
    float s  = wave_sum_f32(e0 + e1);

    cx = wave_sum_f32(cx) * 0.125f;
    cy = wave_sum_f32(cy) * 0.125f;
    cz = wave_sum_f32(cz) * 0.125f;

    float p0 = __shfl(e0, lbl >> 1, 64);
    float p1 = __shfl(e1, lbl >> 1, 64);
    float pm = ((lbl & 1) ? p1 : p0) / s;

    float dx = cx - bx0, dy = cy - bx1, dz = cz - bx2;
    C[bn * Mv + t] = 5.0f * sqrtf(dx * dx + dy * dy + dz * dz) - pm;
}

// ---------------------------------------------------------------------------
// Kernel 2: LAPJV-style LSA, one wave per batch, all state in registers.
// R5 verified structure (gather layout is cache-optimal; DPP reduce; row
// prefetch). R6 critical-path cuts, all assignment-exact vs reference:
//  1. INFV-sentinel used-masking: used/invalid slots carry crow=BIGV and
//     minv=INFV, so the scan needs NO per-slot used test. Equivalent to
//     reference's masked=where(used,INF,minv): minv[used] is dead there
//     except through the INF mask, and cur_used=BIGV-u-v ~1e18 never beats
//     minv, freezing way[used] exactly as the reference does.
//  2. delta via pure f32 DPP min (1 op/step); argmin via equality-search
//     (value==delta, min j) u32 DPP chain overlapped with the u/v/minv
//     update loop (which depends only on delta). First-index-of-min ==
//     jnp.argmin; fminf/min are exact (no rounding).
//  3. readlane (uniform SGPR index) replaces ds_bpermute for u_i0 and the
//     p[] lookup.
// ---------------------------------------------------------------------------
__global__ __launch_bounds__(64) void lsa_kernel(
    const float* __restrict__ C,    // [B, N, M] = [64,900,64]
    float* __restrict__ outPred, float* __restrict__ outTgt)
{
    const int b = blockIdx.x;
    const int t = threadIdx.x;
    const float* cb = C + (size_t)b * Nv * Mv;

    // ---- Phase A: row argmin (lane t = row t+1); 4 ranges, deep unroll
    float mv0 = INFV, mv1 = INFV, mv2 = INFV, mv3 = INFV;
    int   mj0 = 0,    mj1 = 0,    mj2 = 0,    mj3 = 0;
    #pragma unroll 9
    for (int n = 0; n < 225; ++n) {
        float c0 = cb[(size_t)(n      ) * Mv + t];
        float c1 = cb[(size_t)(n + 225) * Mv + t];
        float c2 = cb[(size_t)(n + 450) * Mv + t];
        float c3 = cb[(size_t)(n + 675) * Mv + t];
        if (c0 < mv0) { mv0 = c0; mj0 = n;       }
        if (c1 < mv1) { mv1 = c1; mj1 = n + 225; }
        if (c2 < mv2) { mv2 = c2; mj2 = n + 450; }
        if (c3 < mv3) { mv3 = c3; mj3 = n + 675; }
    }
    float rowmin = mv0; int rown = mj0;
    if (mv1 < rowmin) { rowmin = mv1; rown = mj1; }
    if (mv2 < rowmin) { rowmin = mv2; rown = mj2; }
    if (mv3 < rowmin) { rowmin = mv3; rown = mj3; }

    float u_reg = rowmin;            // lane l holds u[l+1]
    const int jcol = rown + 1;       // column index in 1..900

    // ---- Phase B: duplicate detection (first occurrence wins)
    bool isdup = false;
    #pragma unroll
    for (int s = 1; s < 64; ++s) {
        int oj = __shfl(jcol, (t + 64 - s) & 63, 64);
        isdup |= (oj == jcol) && (s <= t);
    }
    unsigned long long pending = __ballot(isdup);

    int   p_reg[KREG], way_reg[KREG];
    float v_reg[KREG], minv[KREG], crow[KREG];
    #pragma unroll
    for (int k = 0; k < KREG; k++) { p_reg[k] = 0; way_reg[k] = 0; v_reg[k] = 0.f; }

    int rowcol = isdup ? 0 : jcol;   // lane i: column assigned to row i+1

    // scatter winners into distributed p[] (independent iterations)
    #pragma unroll 8
    for (int i = 0; i < 64; ++i) {
        int jb = __shfl(jcol, i, 64);
        if (!((pending >> i) & 1ull) && t == (jb & 63))
            SET15(p_reg, jb >> 6, i + 1);
    }

    // ---- Phase C: Dijkstra phases for conflicted rows only
    while (pending) {
        const int i1v = __ffsll(pending);    // bit pos +1 == row index (1-based)
        pending &= pending - 1;

        unsigned int usedMask = (t == 0) ? 1u : 0u;   // dummy col 0 used
        unsigned long long rowMask = 0;
        #pragma unroll
        for (int k = 0; k < KREG; k++) minv[k] = INFV;

        int j0 = 0;
        int i0 = i1v;

        // initial gather for row i0; j==0 and j>=NCOLS slots get BIGV
        #pragma unroll
        for (int k = 0; k < KREG; k++) {
            int j = t + (k << 6);
            crow[k] = (j >= 1 && j < NCOLS)
                      ? cb[(((size_t)(j - 1)) << 6) + (i0 - 1)] : BIGV;
        }

        while (true) {
            rowMask |= 1ull << (i0 - 1);
            const int sl = __builtin_amdgcn_readfirstlane(i0 - 1);
            const float u_i0 = __int_as_float(
                __builtin_amdgcn_readlane(__float_as_int(u_reg), sl));

            // scan: no used test needed (used/invalid slots: crow=BIGV,
            // minv=INFV -> cur ~1e18 never merges, INFV never wins best
            // while any real slot exists — same as reference's masked INF)
            float bestv = INFV;
            int   bestk = 0;
            #pragma unroll
            for (int k = 0; k < KREG; k++) {
                float cur = (crow[k] - u_i0) - v_reg[k];
                if (cur < minv[k]) { minv[k] = cur; way_reg[k] = j0; }
                if (minv[k] < bestv) { bestv = minv[k]; bestk = k; }
            }

            // delta: fast f32 min chain (exact min, no rounding)
            const float delta = wave_min_f32(bestv);

            // argmin j (first index attaining min), overlaps update loop
            unsigned jc = (bestv == delta)
                          ? (unsigned)(t + (bestk << 6)) : 0xFFFFFFFFu;
            const int j1 = (int)wave_min_u32(jc);

            const int k1 = j1 >> 6, l1 = j1 & 63;   // uniform (SGPR)
            int ptmp; SEL15(p_reg, k1, ptmp);
            const int inext = __builtin_amdgcn_readlane(ptmp, l1);

            // prefetch next row (masked: used slots -> BIGV); off critical path
            const bool newbit = (t == l1);
            unsigned newUsed = usedMask | (newbit ? (1u << k1) : 0u);
            if (inext != 0) {
                const int src = inext - 1;
                #pragma unroll
                for (int k = 0; k < KREG; k++) {
                    int j = t + (k << 6);
                    bool valid = (j >= 1 && j < NCOLS) && !((newUsed >> k) & 1u);
                    crow[k] = valid ? cb[(((size_t)(j - 1)) << 6) + src] : BIGV;
                }
            }

            // dual/distance updates (reference order: used = OLD usedMask;
            // newly-selected slot j1 gets minv=INFV = reference's INF mask)
            if ((rowMask >> t) & 1ull) u_reg += delta;
            #pragma unroll
            for (int k = 0; k < KREG; k++) {
                bool used  = (usedMask >> k) & 1u;
                bool isnew = newbit && (k == k1);
                v_reg[k] = used ? v_reg[k] - delta : v_reg[k];
                float mupd = used ? minv[k] : minv[k] - delta;
                minv[k] = isnew ? INFV : mupd;
            }
            usedMask = newUsed;

            j0 = j1;
            i0 = inext;
            if (i0 == 0) break;              // free column reached
        }

        // backtrack: reassign columns along augmenting path
        while (j0 != 0) {
            const int k0 = j0 >> 6, l0 = j0 & 63;
            int wtmp; SEL15(way_reg, k0, wtmp);
            const int jprev = __shfl(wtmp, l0, 64);
            int pv;
            if (jprev == 0) {
                pv = i1v;
            } else {
                int ptmp; SEL15(p_reg, jprev >> 6, ptmp);
                pv = __shfl(ptmp, jprev & 63, 64);
            }
            if (t == l0) SET15(p_reg, k0, pv);
            if (t == pv - 1) rowcol = j0;    // maintain row->column mirror
            j0 = jprev;
        }
    }

    outPred[b * Mv + t] = (float)(rowcol - 1);
    outTgt[b * Mv + t]  = (float)t;
}

// ---------------------------------------------------------------------------
extern "C" void kernel_launch(void* const* d_in, const int* in_sizes, int n_in,
                              void* d_out, int out_size, void* d_ws, size_t ws_size,
                              hipStream_t stream)
{
    (void)in_sizes; (void)n_in; (void)out_size; (void)d_ws; (void)ws_size;

    const float* logits  = (const float*)d_in[0];   // [64,900,128] f32
    const float* corners = (const float*)d_in[1];   // [64,900,8,3] f32
    const int*   labels  = (const int*)  d_in[2];   // [64,64] i32
    const float* boxes   = (const float*)d_in[3];   // [64,64,7] f32

    float* out  = (float*)d_out;
    float* Cc   = out;                               // [64,900,64]
    float* pred = out + (size_t)Bv * Nv * Mv;        // [64,64] as f32
    float* tgt  = pred + (size_t)Bv * Mv;            // [64,64] as f32

    cost_kernel<<<dim3(225, Bv), 256, 0, stream>>>(logits, corners, labels, boxes, Cc);
    lsa_kernel<<<Bv, 64, 0, stream>>>(Cc, pred, tgt);
}